// Round 5
// baseline (481.989 us; speedup 1.0000x reference)
//
#include <hip/hip_runtime.h>
#include <hip/hip_bf16.h>

typedef __bf16 bf16_t;
typedef __bf16 bf16x8 __attribute__((ext_vector_type(8)));
typedef float f32x4 __attribute__((ext_vector_type(4)));

#define BATCH 4
#define NSEQ 2048
#define DMODEL 512
#define HEADS 8
#define DHEAD 64
#define QKVN 1536
#define NN ((size_t)NSEQ * NSEQ)

// LDS-only barrier: does NOT drain vmcnt -> in-flight global loads survive.
#define BAR() asm volatile("s_waitcnt lgkmcnt(0)\n\ts_barrier" ::: "memory")
// Loads issued textually before this cannot sink past it.
#define PIN() asm volatile("" ::: "memory")

__device__ __forceinline__ void gload_lds16(const void* g, void* l) {
  __builtin_amdgcn_global_load_lds((const __attribute__((address_space(1))) void*)g,
                                   (__attribute__((address_space(3))) void*)l, 16, 0, 0);
}

__device__ __forceinline__ f32x4 mfma16(bf16x8 a, bf16x8 b, f32x4 c) {
  return __builtin_amdgcn_mfma_f32_16x16x32_bf16(a, b, c, 0, 0, 0);
}

// ---------------- convert kernels ----------------
__global__ __launch_bounds__(256) void cvt_bf16_kernel(const float* __restrict__ in,
                                                       bf16_t* __restrict__ out, int n4) {
  int i = blockIdx.x * 256 + threadIdx.x;
  if (i < n4) {
    float4 v = ((const float4*)in)[i];
    union { bf16_t b[4]; uint2 u; } pk;
    pk.b[0] = (bf16_t)v.x; pk.b[1] = (bf16_t)v.y;
    pk.b[2] = (bf16_t)v.z; pk.b[3] = (bf16_t)v.w;
    ((uint2*)out)[i] = pk.u;
  }
}

// Both weight transposes in one launch. z=0: Wqkv [512x1536] (Q cols pre-scaled
// by 1/8 to fold the softmax scale); z=1: Wout [512x512].
__global__ __launch_bounds__(256) void cvt_transpose2_kernel(
    const float* __restrict__ Wqkv, bf16_t* __restrict__ WqkvT,
    const float* __restrict__ Wout, bf16_t* __restrict__ WoutT) {
  __shared__ float tile[64][65];
  const float* in; bf16_t* out; int C, scaleRows;
  if (blockIdx.z == 0) { in = Wqkv; out = WqkvT; C = QKVN; scaleRows = DMODEL; }
  else                 { in = Wout; out = WoutT; C = DMODEL; scaleRows = 0; }
  const int R = DMODEL;
  const int r0 = blockIdx.y * 64, c0 = blockIdx.x * 64;
  if (c0 >= C) return;
  const int tx = threadIdx.x & 63, tg = threadIdx.x >> 6;
#pragma unroll
  for (int i = 0; i < 16; i++) {
    int rr = tg * 16 + i;
    tile[rr][tx] = in[(size_t)(r0 + rr) * C + c0 + tx];
  }
  __syncthreads();
#pragma unroll
  for (int i = 0; i < 16; i++) {
    int cc = tg * 16 + i;
    float v = tile[tx][cc];
    if (c0 + cc < scaleRows) v *= 0.125f;
    out[(size_t)(c0 + cc) * R + r0 + tx] = (bf16_t)v;
  }
}

// ---------------- GEMM: C[M,N] = A[M,K] * Bt[N,K]^T (+bias) ----------------
template<int BIAS, int OUTF32>
__global__ __launch_bounds__(256) void gemm128_kernel(const bf16_t* __restrict__ A,
    const bf16_t* __restrict__ Bt, void* __restrict__ Cout,
    const float* __restrict__ bias, int M, int N, int K) {
  __shared__ __align__(16) bf16_t As[128 * 64];
  __shared__ __align__(16) bf16_t Bs[128 * 64];
  const int tid = threadIdx.x;
  const int w = tid >> 6, lane = tid & 63, quad = lane >> 4, l16 = lane & 15;
  const int wm = w & 1, wn = w >> 1;
  const int m0 = blockIdx.x * 128, n0 = blockIdx.y * 128;
  f32x4 acc[4][4] = {};
  int srow[4], scg[4];
#pragma unroll
  for (int t = 0; t < 4; t++) {
    int s = (w * 4 + t) * 64 + lane;
    srow[t] = s >> 3;
    scg[t] = (s & 7) ^ (srow[t] & 7);
  }
  for (int k0 = 0; k0 < K; k0 += 64) {
#pragma unroll
    for (int t = 0; t < 4; t++) {
      gload_lds16(&A[(size_t)(m0 + srow[t]) * K + k0 + scg[t] * 8], &As[(w * 4 + t) * 512]);
      gload_lds16(&Bt[(size_t)(n0 + srow[t]) * K + k0 + scg[t] * 8], &Bs[(w * 4 + t) * 512]);
    }
    __syncthreads();
    bf16x8 af[4][2], bfr[4][2];
#pragma unroll
    for (int mt = 0; mt < 4; mt++) {
      int row = wm * 64 + mt * 16 + l16;
#pragma unroll
      for (int kh = 0; kh < 2; kh++)
        af[mt][kh] = *(const bf16x8*)&As[(row * 8 + ((kh * 4 + quad) ^ (row & 7))) * 8];
    }
#pragma unroll
    for (int nt = 0; nt < 4; nt++) {
      int row = wn * 64 + nt * 16 + l16;
#pragma unroll
      for (int kh = 0; kh < 2; kh++)
        bfr[nt][kh] = *(const bf16x8*)&Bs[(row * 8 + ((kh * 4 + quad) ^ (row & 7))) * 8];
    }
#pragma unroll
    for (int mt = 0; mt < 4; mt++)
#pragma unroll
      for (int nt = 0; nt < 4; nt++) {
        acc[mt][nt] = mfma16(af[mt][0], bfr[nt][0], acc[mt][nt]);
        acc[mt][nt] = mfma16(af[mt][1], bfr[nt][1], acc[mt][nt]);
      }
    __syncthreads();
  }
#pragma unroll
  for (int nt = 0; nt < 4; nt++) {
    int col = n0 + wn * 64 + nt * 16 + l16;
    float bv = BIAS ? bias[col] : 0.0f;
#pragma unroll
    for (int mt = 0; mt < 4; mt++) {
#pragma unroll
      for (int rr = 0; rr < 4; rr++) {
        int row = m0 + wm * 64 + mt * 16 + quad * 4 + rr;
        float v = acc[mt][nt][rr] + bv;
        if (OUTF32) ((float*)Cout)[(size_t)row * N + col] = v;
        else        ((bf16_t*)Cout)[(size_t)row * N + col] = (bf16_t)v;
      }
    }
  }
}

// ---------------- fused flash attention with conv-bias ----------------
// grid: 1024 blocks; bid = h*128 + b*32 + it (head-siblings -> same XCD, all
// blocks co-resident at 4/CU -> cd tile served from L2 for 8 heads).
// cd path: each thread loads its 64x64x3 tile slice as 12 dwordx4 (wide, deep
// MLP), combines channels+rel_b in fp32, stages combined bias as fp16 in LDS;
// MFMA C-fragment lanes read 16 scalars each. 3 LDS-only barriers/iter.
__global__ __launch_bounds__(256, 4) void attn_kernel(const bf16_t* __restrict__ qkv,
    const float* __restrict__ cd, const float* __restrict__ rel_w,
    const float* __restrict__ rel_b, bf16_t* __restrict__ ao) {
  __shared__ __align__(16) bf16_t Ks[64][72];      // K tile: [j][d]
  __shared__ __align__(16) bf16_t Vts[64][72];     // V^T tile: [d][j], col XOR-swizzled
  __shared__ __align__(16) bf16_t Ps[64][72];      // P: [i][j], col XOR-swizzled
  __shared__ __align__(16) _Float16 BiasL[64][68]; // combined conv bias, fp16
  const int tid = threadIdx.x;
  const int w = tid >> 6, lane = tid & 63, quad = lane >> 4, l16 = lane & 15;
  const int bid = blockIdx.x;
  const int h = bid >> 7, b = (bid >> 5) & 3, it = bid & 31;

  // Q fragments (A-layout); Wqkv Q-columns pre-scaled by 1/8.
  const size_t qoff = (size_t)(b * NSEQ + it * 64 + w * 16 + l16) * QKVN + h * DHEAD;
  bf16x8 q0 = *(const bf16x8*)&qkv[qoff + quad * 8];
  bf16x8 q1 = *(const bf16x8*)&qkv[qoff + 32 + quad * 8];

  const float rw0 = rel_w[h * 3 + 0], rw1 = rel_w[h * 3 + 1], rw2 = rel_w[h * 3 + 2];
  const float rb = rel_b[h];

  f32x4 o[4] = {};
  float m_r[4], l_r[4];
#pragma unroll
  for (int r = 0; r < 4; r++) { m_r[r] = -1e30f; l_r[r] = 0.0f; }

  const int sr = tid >> 3, sg = tid & 7;
  const size_t kbase = (size_t)b * NSEQ * QKVN + DMODEL + h * DHEAD;

  // cd slice for this THREAD (not lane-fragment): row=tid>>2, 16 cols per thread
  const int crow = tid >> 2, ccg = tid & 3;
  const float* cdt = cd + (size_t)b * 3 * NN + (size_t)(it * 64 + crow) * NSEQ + ccg * 16;

#define COMBINE_WRITE() do {                                                       \
  _Pragma("unroll") for (int g = 0; g < 4; g++) {                                  \
    union { _Float16 hh[4]; uint2 u; } pk;                                         \
    pk.hh[0] = (_Float16)fmaf(rw0, cda[0][g].x, fmaf(rw1, cda[1][g].x, fmaf(rw2, cda[2][g].x, rb))); \
    pk.hh[1] = (_Float16)fmaf(rw0, cda[0][g].y, fmaf(rw1, cda[1][g].y, fmaf(rw2, cda[2][g].y, rb))); \
    pk.hh[2] = (_Float16)fmaf(rw0, cda[0][g].z, fmaf(rw1, cda[1][g].z, fmaf(rw2, cda[2][g].z, rb))); \
    pk.hh[3] = (_Float16)fmaf(rw0, cda[0][g].w, fmaf(rw1, cda[1][g].w, fmaf(rw2, cda[2][g].w, rb))); \
    *(uint2*)&BiasL[crow][ccg * 16 + g * 4] = pk.u;                                \
  } } while (0)

  // ---- prologue: K/V tile 0 -> regs; cd tile 0 -> combine -> BiasL ----
  uint4 k0r, k1r, v0r, v1r;
  {
    const bf16_t* p = &qkv[kbase + (size_t)sr * QKVN + sg * 8];
    k0r = *(const uint4*)p;               v0r = *(const uint4*)(p + DMODEL);
    k1r = *(const uint4*)(p + (size_t)32 * QKVN);
    v1r = *(const uint4*)(p + (size_t)32 * QKVN + DMODEL);
  }
  {
    float4 cda[3][4];
#pragma unroll
    for (int ch = 0; ch < 3; ch++)
#pragma unroll
      for (int g = 0; g < 4; g++)
        cda[ch][g] = *(const float4*)&cdt[ch * NN + g * 4];
    COMBINE_WRITE();
  }

  for (int jt = 0; jt < 32; jt++) {
    // ---- staged K/V regs -> LDS ----
    *(uint4*)&Ks[sr][sg * 8]      = k0r;
    *(uint4*)&Ks[sr + 32][sg * 8] = k1r;
    {
      union { bf16_t e[8]; uint4 u; } va, vb; va.u = v0r; vb.u = v1r;
      const int pc = sr ^ ((sg & 3) << 3);
#pragma unroll
      for (int e2 = 0; e2 < 8; e2++) {
        Vts[sg * 8 + e2][pc]      = va.e[e2];
        Vts[sg * 8 + e2][pc + 32] = vb.e[e2];
      }
    }
    BAR();   // BAR1: Ks/Vts(jt) + BiasL(jt) visible

    // ---- issue next tile's loads (wide; live across QK) ----
    float4 cda[3][4];
    if (jt < 31) {
      const bf16_t* p = &qkv[kbase + (size_t)((jt + 1) * 64 + sr) * QKVN + sg * 8];
      k0r = *(const uint4*)p;               v0r = *(const uint4*)(p + DMODEL);
      k1r = *(const uint4*)(p + (size_t)32 * QKVN);
      v1r = *(const uint4*)(p + (size_t)32 * QKVN + DMODEL);
      const float* cc = cdt + (jt + 1) * 64;
#pragma unroll
      for (int ch = 0; ch < 3; ch++)
#pragma unroll
        for (int g = 0; g < 4; g++)
          cda[ch][g] = *(const float4*)&cc[ch * NN + g * 4];
    }
    PIN();   // loads cannot sink below this point

    // ---- s = bias (from LDS fp16) then += Q*K^T ----
    f32x4 s[4];
#pragma unroll
    for (int ct = 0; ct < 4; ct++)
#pragma unroll
      for (int r = 0; r < 4; r++)
        s[ct][r] = (float)BiasL[w * 16 + quad * 4 + r][ct * 16 + l16];
#pragma unroll
    for (int ct = 0; ct < 4; ct++) {
      bf16x8 b0 = *(const bf16x8*)&Ks[ct * 16 + l16][quad * 8];
      bf16x8 b1 = *(const bf16x8*)&Ks[ct * 16 + l16][32 + quad * 8];
      s[ct] = mfma16(q0, b0, s[ct]);
      s[ct] = mfma16(q1, b1, s[ct]);
    }
    BAR();   // BAR2: all waves consumed BiasL(jt)

    // ---- combine + write BiasL(jt+1) ----
    if (jt < 31) COMBINE_WRITE();

    // ---- online softmax (per quad-row) ----
#pragma unroll
    for (int r = 0; r < 4; r++) {
      float mx = fmaxf(fmaxf(s[0][r], s[1][r]), fmaxf(s[2][r], s[3][r]));
#pragma unroll
      for (int off = 8; off >= 1; off >>= 1) mx = fmaxf(mx, __shfl_xor(mx, off, 64));
      float mnew = fmaxf(m_r[r], mx);
      float alpha = __expf(m_r[r] - mnew);
      float rsum = 0.0f;
#pragma unroll
      for (int ct = 0; ct < 4; ct++) {
        float p = __expf(s[ct][r] - mnew);
        s[ct][r] = p; rsum += p;
      }
#pragma unroll
      for (int off = 8; off >= 1; off >>= 1) rsum += __shfl_xor(rsum, off, 64);
      l_r[r] = l_r[r] * alpha + rsum;
      m_r[r] = mnew;
#pragma unroll
      for (int dt = 0; dt < 4; dt++) o[dt][r] *= alpha;
    }

    // ---- P: C-layout -> LDS (swizzled) -> A-layout (wave-private slice) ----
#pragma unroll
    for (int ct = 0; ct < 4; ct++)
#pragma unroll
      for (int rr = 0; rr < 4; rr++)
        Ps[w * 16 + quad * 4 + rr][(ct * 16 + l16) ^ (quad << 3)] = (bf16_t)s[ct][rr];

    const int psw = ((l16 >> 2) & 3) << 3;
    bf16x8 p0 = *(const bf16x8*)&Ps[w * 16 + l16][(quad * 8) ^ psw];
    bf16x8 p1 = *(const bf16x8*)&Ps[w * 16 + l16][32 + ((quad * 8) ^ psw)];
#pragma unroll
    for (int dt = 0; dt < 4; dt++) {
      const int row = dt * 16 + l16;
      const int vsw = ((row >> 3) & 3) << 3;
      bf16x8 v0 = *(const bf16x8*)&Vts[row][(quad * 8) ^ vsw];
      bf16x8 v1 = *(const bf16x8*)&Vts[row][32 + ((quad * 8) ^ vsw)];
      o[dt] = mfma16(p0, v0, o[dt]);
      o[dt] = mfma16(p1, v1, o[dt]);
    }
    BAR();   // BAR3: Ks/Vts readers done; BiasL(jt+1) ordered before next read
  }

  // ---- epilogue ----
  float inv[4];
#pragma unroll
  for (int r = 0; r < 4; r++) inv[r] = 1.0f / l_r[r];
#pragma unroll
  for (int dt = 0; dt < 4; dt++) {
    int col = h * DHEAD + dt * 16 + l16;
#pragma unroll
    for (int rr = 0; rr < 4; rr++) {
      int row = b * NSEQ + it * 64 + w * 16 + quad * 4 + rr;
      ao[(size_t)row * DMODEL + col] = (bf16_t)(o[dt][rr] * inv[rr]);
    }
  }
#undef COMBINE_WRITE
}

// ---------------- launch ----------------
extern "C" void kernel_launch(void* const* d_in, const int* in_sizes, int n_in,
                              void* d_out, int out_size, void* d_ws, size_t ws_size,
                              hipStream_t stream) {
  const float* x     = (const float*)d_in[0];
  const float* cd    = (const float*)d_in[1];
  const float* Wqkv  = (const float*)d_in[2];
  const float* Wout  = (const float*)d_in[3];
  const float* bout  = (const float*)d_in[4];
  const float* rel_w = (const float*)d_in[5];
  const float* rel_b = (const float*)d_in[6];
  float* out = (float*)d_out;

  char* ws = (char*)d_ws;
  const size_t M = (size_t)BATCH * NSEQ;                 // 8192
  bf16_t* xb    = (bf16_t*)ws;                                            // 8.0 MB
  bf16_t* WqkvT = (bf16_t*)(ws + 8388608);                                // 1.5 MB
  bf16_t* WoutT = (bf16_t*)(ws + 8388608 + 1572864);                      // 0.5 MB
  bf16_t* qkv   = (bf16_t*)(ws + 8388608 + 1572864 + 524288);             // 24 MB
  bf16_t* ao    = (bf16_t*)(ws + 8388608 + 1572864 + 524288 + 25165824);  // 8 MB

  cvt_bf16_kernel<<<(int)(M * DMODEL / 4 / 256), 256, 0, stream>>>(x, xb, (int)(M * DMODEL / 4));
  cvt_transpose2_kernel<<<dim3(QKVN / 64, DMODEL / 64, 2), 256, 0, stream>>>(
      Wqkv, WqkvT, Wout, WoutT);

  gemm128_kernel<0, 0><<<dim3(M / 128, QKVN / 128), 256, 0, stream>>>(
      xb, WqkvT, (void*)qkv, nullptr, (int)M, QKVN, DMODEL);

  attn_kernel<<<BATCH * 32 * HEADS, 256, 0, stream>>>(qkv, cd, rel_w, rel_b, ao);

  gemm128_kernel<1, 1><<<dim3(M / 128, DMODEL / 128), 256, 0, stream>>>(
      ao, WoutT, (void*)out, bout, (int)M, DMODEL, DMODEL);
}